// Round 11
// baseline (133.319 us; speedup 1.0000x reference)
//
#include <hip/hip_runtime.h>

#define TT 8
#define NN 2048
#define SS 8192
#define MM (NN * SS)   // 16777216 elements

// Bernoulli integer thresholds: p * 2^23 (all probabilities are dyadic k/128)
#define TH_CAP10  655360u    // 10/128 * 2^23  (ucapture, uminus)
#define TH_SEARCH 65536u     //  1/128 * 2^23
#define TH_BACK   6291456u   // 96/128 * 2^23
#define TH_MIN    262144u    //  4/128 * 2^23

typedef int      __attribute__((ext_vector_type(4))) intx4;
typedef float    __attribute__((ext_vector_type(4))) floatx4;
typedef unsigned __attribute__((ext_vector_type(4))) uintx4;
typedef unsigned __attribute__((ext_vector_type(2))) uintx2;

// 4 branch rows x 40 words (160 B stride -> rows on disjoint bank groups
// {0,8,16,24}: conflict-free ds_read_b128 broadcast).
struct Tbl { unsigned v[160]; };

// 1-op rotate (compiler also pattern-matches this; alignbit is explicit).
#define ROTL(x, r) __builtin_amdgcn_alignbit((x), (x), 32u - (r))

// One Threefry round position applied to THREE independent chains in
// lockstep: consecutive VALU insts are independent -> dependent-op latency
// is hidden at issue rate (the M2/ILP experiment).
#define STEP3(r)                                            \
  a0 += a1; b0 += b1; c0 += c1;                             \
  a1 = ROTL(a1, r); b1 = ROTL(b1, r); c1 = ROTL(c1, r);     \
  a1 ^= a0; b1 ^= b0; c1 ^= c0;

#define R4_3(ra, rb, rc, rd) STEP3(ra) STEP3(rb) STEP3(rc) STEP3(rd)

// 3-chain injection from schedule quads (all key arithmetic pre-done on host)
#define INJ3(qa, qb, qc, lo, hi)                            \
  a0 += qa.lo; a1 += qa.hi;                                 \
  b0 += qb.lo; b1 += qb.hi;                                 \
  c0 += qc.lo; c1 += qc.hi;

// Host-side full Threefry (key derivation only).
static void tf2x32_host(unsigned k0, unsigned k1, unsigned x0, unsigned x1,
                        unsigned& o0, unsigned& o1) {
  const unsigned ks2 = k0 ^ k1 ^ 0x1BD11BDAu;
  x0 += k0; x1 += k1;
#define TFRH(r) { x0 += x1; x1 = (x1 << (r)) | (x1 >> (32 - (r))); x1 ^= x0; }
  TFRH(13) TFRH(15) TFRH(26) TFRH(6)
  x0 += k1;  x1 += ks2 + 1u;
  TFRH(17) TFRH(29) TFRH(16) TFRH(24)
  x0 += ks2; x1 += k0 + 2u;
  TFRH(13) TFRH(15) TFRH(26) TFRH(6)
  x0 += k0;  x1 += k1 + 3u;
  TFRH(17) TFRH(29) TFRH(16) TFRH(24)
  x0 += k1;  x1 += ks2 + 4u;
  TFRH(13) TFRH(15) TFRH(26) TFRH(6)
  x0 += ks2; x1 += k0 + 5u;
#undef TFRH
  o0 = x0; o1 = x1;
}

__global__ __launch_bounds__(256, 4) void ModSTDP_58823872086838_kernel(
    const int* __restrict__ inS,    // [T, N, S] int32 0/1
    const int* __restrict__ outS,   // [T, N]    int32 0/1
    const float* __restrict__ W,    // [N, S]
    float* __restrict__ out,        // [N, S]
    Tbl tb)
{
  __shared__ __align__(16) unsigned tbl[160];
  if (threadIdx.x < 160) tbl[threadIdx.x] = tb.v[threadIdx.x];
  __syncthreads();

  const unsigned tid  = blockIdx.x * blockDim.x + threadIdx.x;
  const unsigned base = tid << 2;               // 4 elements per thread
  // Row index is wave-uniform: scalarize so osum loads ride the SMEM pipe.
  const unsigned n    = __builtin_amdgcn_readfirstlane(base >> 13);

  int osum = 0;
#pragma unroll
  for (int t = 0; t < TT; ++t) osum += outS[t * NN + n];
  const bool outF = osum > 0;

  const floatx4 w4 = *reinterpret_cast<const floatx4*>(W + base);

  intx4 sp[TT];
#pragma unroll
  for (int t = 0; t < TT; ++t)
    sp[t] = *reinterpret_cast<const intx4*>(inS + (size_t)t * MM + base);

  int cnt[4] = {0, 0, 0, 0};
#pragma unroll
  for (int t = 0; t < TT; ++t) {
#pragma unroll
    for (int e = 0; e < 4; ++e) cnt[e] += sp[t][e];
  }

  float res[4];
#pragma unroll
  for (int e = 0; e < 4; ++e) {
    const unsigned j = base + (unsigned)e;
    const float w = fminf(fmaxf(w4[e], 0.0f), 8.0f);
    const int c = cnt[e];
    const bool inF = c > 0;
    const bool active = inF | outF;
    // branch index: 0=capture 1=minus 2=search 3=backoff
    // (in_t <= out_t) <=> (8-c <= 8-o) <=> (c >= o)
    const unsigned idx = inF ? (outF ? ((c >= osum) ? 0u : 1u) : 2u) : 3u;
    const unsigned* row = tbl + idx * 40u;

    // p_plus / p_minus exactly as XLA (no FMA contraction)
    const float wn = w * 0.125f;
    const float pp = __fmul_rn(wn, __fsub_rn(2.0f, wn));
    const float pm = __fmul_rn(__fsub_rn(1.0f, wn), __fadd_rn(1.0f, wn));
    const float pA = (idx & 1u) ? pm : pp;   // odd rows use fminus

    // All nine schedule quads up front (DS pipe; one lgkmcnt before use),
    // then 3 chains (A=fplus/fminus, B=gate, C=umin) fully interleaved.
    const uintx4 sa0 = *reinterpret_cast<const uintx4*>(row);
    const uintx4 sa1 = *reinterpret_cast<const uintx4*>(row + 4);
    const uintx4 sa2 = *reinterpret_cast<const uintx4*>(row + 8);
    const uintx4 sb0 = *reinterpret_cast<const uintx4*>(row + 12);
    const uintx4 sb1 = *reinterpret_cast<const uintx4*>(row + 16);
    const uintx4 sb2 = *reinterpret_cast<const uintx4*>(row + 20);
    const uintx4 sc0 = *reinterpret_cast<const uintx4*>(row + 24);
    const uintx4 sc1 = *reinterpret_cast<const uintx4*>(row + 28);
    const uintx4 sc2 = *reinterpret_cast<const uintx4*>(row + 32);
    const uintx2 tc  = *reinterpret_cast<const uintx2*>(row + 36);

    unsigned a0 = sa0.x, a1 = j + sa0.y;
    unsigned b0 = sb0.x, b1 = j + sb0.y;
    unsigned c0 = sc0.x, c1 = j + sc0.y;

    R4_3(13, 15, 26, 6)
    INJ3(sa0, sb0, sc0, z, w)
    R4_3(17, 29, 16, 24)
    INJ3(sa1, sb1, sc1, x, y)
    R4_3(13, 15, 26, 6)
    INJ3(sa1, sb1, sc1, z, w)
    R4_3(17, 29, 16, 24)
    INJ3(sa2, sb2, sc2, x, y)
    R4_3(13, 15, 26, 6)
    INJ3(sa2, sb2, sc2, z, w)

    const unsigned bitsA = a0 ^ a1;          // partitionable: x0 ^ x1
    const unsigned bitsB = b0 ^ b1;
    const unsigned bitsC = c0 ^ c1;

    const float u = __uint_as_float((bitsA >> 9) | 0x3f800000u) - 1.0f;
    const bool fab  = u < pA;
    const bool gate = (bitsB >> 9) < tc.x;
    const bool um   = (bitsC >> 9) < TH_MIN;

    const bool doit = active & gate & (fab | um);
    res[e] = doit ? __fadd_rn(w, __uint_as_float(tc.y)) : w;
  }

  floatx4 r;
  r.x = res[0]; r.y = res[1]; r.z = res[2]; r.w = res[3];
  __builtin_nontemporal_store(r, reinterpret_cast<floatx4*>(out + base));
}

extern "C" void kernel_launch(void* const* d_in, const int* in_sizes, int n_in,
                              void* d_out, int out_size, void* d_ws, size_t ws_size,
                              hipStream_t stream) {
  const int*   inS  = (const int*)d_in[0];
  const int*   outS = (const int*)d_in[1];
  const float* W    = (const float*)d_in[2];
  float*       out  = (float*)d_out;

  // Host-side key derivation (pure arithmetic — graph-capture safe).
  // jax.random.key(42) -> (0, 42). Fold-like split (threefry_partitionable):
  // rk[i] = threefry(key, (0, i));  k7{a,b,c} = threefry(rk7, (0, {0,1,2}))
  unsigned kp[20];
  {
    unsigned rk[16];
    for (unsigned i = 0; i < 8; ++i) {
      unsigned o0, o1;
      tf2x32_host(0u, 42u, 0u, i, o0, o1);
      rk[2 * i] = o0; rk[2 * i + 1] = o1;
    }
    for (int i = 0; i < 14; ++i) kp[i] = rk[i];      // rk0..rk6
    for (unsigned i = 0; i < 3; ++i) {
      unsigned o0, o1;
      tf2x32_host(rk[14], rk[15], 0u, i, o0, o1);
      kp[14 + 2 * i] = o0; kp[15 + 2 * i] = o1;
    }
  }

  // Emit the 12-word injection schedule for key (K0,K1):
  // inj0=(K0,K1) inj1=(K1,ks2+1) inj2=(ks2,K0+2) inj3=(K0,K1+3)
  // inj4=(K1,ks2+4) inj5=(ks2,K0+5)
  auto emit = [](unsigned* d, unsigned K0, unsigned K1) {
    const unsigned ks2 = K0 ^ K1 ^ 0x1BD11BDAu;
    d[0] = K0;  d[1] = K1;       d[2]  = K1;  d[3]  = ks2 + 1u;
    d[4] = ks2; d[5] = K0 + 2u;  d[6]  = K0;  d[7]  = K1 + 3u;
    d[8] = K1;  d[9] = ks2 + 4u; d[10] = ks2; d[11] = K0 + 5u;
  };

  // rows: {drawA keys, drawB keys, drawC keys, thB, sgn}
  Tbl tb;
  const unsigned rowspec[4][8] = {
    {0, 1, 4, 5, 12, 13, TH_CAP10,  0x3f800000u},   // capture  +1
    {2, 3, 6, 7, 14, 15, TH_CAP10,  0xbf800000u},   // minus    -1
    {0, 1, 8, 9, 16, 17, TH_SEARCH, 0x3f800000u},   // search   +1
    {2, 3, 10, 11, 18, 19, TH_BACK, 0xbf800000u},   // backoff  -1
  };
  for (int r = 0; r < 4; ++r) {
    unsigned* d = tb.v + r * 40;
    emit(d,      kp[rowspec[r][0]], kp[rowspec[r][1]]);
    emit(d + 12, kp[rowspec[r][2]], kp[rowspec[r][3]]);
    emit(d + 24, kp[rowspec[r][4]], kp[rowspec[r][5]]);
    d[36] = rowspec[r][6];
    d[37] = rowspec[r][7];
    d[38] = 0; d[39] = 0;
  }

  const int threads = MM / 4;
  dim3 block(256), grid(threads / 256);
  ModSTDP_58823872086838_kernel<<<grid, block, 0, stream>>>(inS, outS, W, out, tb);
}

// Round 12
// 130.822 us; speedup vs baseline: 1.0191x; 1.0191x over previous
//
#include <hip/hip_runtime.h>

#define TT 8
#define NN 2048
#define SS 8192
#define MM (NN * SS)   // 16777216 elements

// Bernoulli integer thresholds: p * 2^23 (all probabilities are dyadic k/128)
#define TH_CAP10  655360u    // 10/128 * 2^23  (ucapture, uminus)
#define TH_SEARCH 65536u     //  1/128 * 2^23
#define TH_BACK   6291456u   // 96/128 * 2^23
#define TH_MIN    262144u    //  4/128 * 2^23

typedef int      __attribute__((ext_vector_type(4))) intx4;
typedef float    __attribute__((ext_vector_type(4))) floatx4;
typedef unsigned __attribute__((ext_vector_type(4))) uintx4;
typedef unsigned __attribute__((ext_vector_type(2))) uintx2;

// 4 branch rows x 40 words. Row layout:
//  [0:12)  draw-A (fplus/fminus) round-key schedule
//  [12:24) draw-B (gate)        round-key schedule
//  [24:36) draw-C (umin)        round-key schedule
//  [36] thB  [37] sgn_bits  [38:40) pad
// Stride 40 words = 160 B -> rows start at banks {0,8,16,24}: the <=4
// distinct per-lane addresses of each ds_read_b128 hit disjoint banks
// (conflict-free broadcast).
struct Tbl { unsigned v[160]; };

// 1-op rotate: v_alignbit_b32 (measured best config, R9: 130.6 us;
// R10's v_perm variant and R11's ILP-interleave both regressed).
#define ROTL(x, r) __builtin_amdgcn_alignbit((x), (x), 32u - (r))

#define R4(x0, x1, ra, rb, rc, rd)                   \
  x0 += x1; x1 = ROTL(x1, ra); x1 ^= x0;             \
  x0 += x1; x1 = ROTL(x1, rb); x1 ^= x0;             \
  x0 += x1; x1 = ROTL(x1, rc); x1 ^= x0;             \
  x0 += x1; x1 = ROTL(x1, rd); x1 ^= x0;

// Threefry-2x32 on counter (0, j) with a precomputed injection schedule
// s0..s2 (12 words: all ks2/+1..+5 arithmetic done on host). Returns x0^x1.
__device__ __forceinline__ unsigned tf_sched(uintx4 s0, uintx4 s1, uintx4 s2,
                                             unsigned j) {
  unsigned x0 = s0.x;            // 0 + k0
  unsigned x1 = j + s0.y;        // j + k1
  R4(x0, x1, 13, 15, 26, 6)
  x0 += s0.z; x1 += s0.w;        // (k1, ks2+1)
  R4(x0, x1, 17, 29, 16, 24)
  x0 += s1.x; x1 += s1.y;        // (ks2, k0+2)
  R4(x0, x1, 13, 15, 26, 6)
  x0 += s1.z; x1 += s1.w;        // (k0, k1+3)
  R4(x0, x1, 17, 29, 16, 24)
  x0 += s2.x; x1 += s2.y;        // (k1, ks2+4)
  R4(x0, x1, 13, 15, 26, 6)
  x0 += s2.z; x1 += s2.w;        // (ks2, k0+5)
  return x0 ^ x1;                // partitionable random_bits: x0 ^ x1
}

// Host-side full Threefry (key derivation only).
static void tf2x32_host(unsigned k0, unsigned k1, unsigned x0, unsigned x1,
                        unsigned& o0, unsigned& o1) {
  const unsigned ks2 = k0 ^ k1 ^ 0x1BD11BDAu;
  x0 += k0; x1 += k1;
#define TFRH(r) { x0 += x1; x1 = (x1 << (r)) | (x1 >> (32 - (r))); x1 ^= x0; }
  TFRH(13) TFRH(15) TFRH(26) TFRH(6)
  x0 += k1;  x1 += ks2 + 1u;
  TFRH(17) TFRH(29) TFRH(16) TFRH(24)
  x0 += ks2; x1 += k0 + 2u;
  TFRH(13) TFRH(15) TFRH(26) TFRH(6)
  x0 += k0;  x1 += k1 + 3u;
  TFRH(17) TFRH(29) TFRH(16) TFRH(24)
  x0 += k1;  x1 += ks2 + 4u;
  TFRH(13) TFRH(15) TFRH(26) TFRH(6)
  x0 += ks2; x1 += k0 + 5u;
#undef TFRH
  o0 = x0; o1 = x1;
}

__global__ __launch_bounds__(256) void ModSTDP_58823872086838_kernel(
    const int* __restrict__ inS,    // [T, N, S] int32 0/1
    const int* __restrict__ outS,   // [T, N]    int32 0/1
    const float* __restrict__ W,    // [N, S]
    float* __restrict__ out,        // [N, S]
    Tbl tb)
{
  __shared__ __align__(16) unsigned tbl[160];
  if (threadIdx.x < 160) tbl[threadIdx.x] = tb.v[threadIdx.x];
  __syncthreads();

  const unsigned tid  = blockIdx.x * blockDim.x + threadIdx.x;
  const unsigned base = tid << 2;               // 4 elements per thread
  const unsigned n    = base >> 13;             // row (S = 8192 = 2^13)

  // Row output-spike count: wave-uniform loads (64 KB table, L1/L2-hot)
  int osum = 0;
#pragma unroll
  for (int t = 0; t < TT; ++t) osum += outS[t * NN + n];
  const bool outF = osum > 0;

  const floatx4 w4 = *reinterpret_cast<const floatx4*>(W + base);

  intx4 sp[TT];
#pragma unroll
  for (int t = 0; t < TT; ++t)
    sp[t] = *reinterpret_cast<const intx4*>(inS + (size_t)t * MM + base);

  int cnt[4] = {0, 0, 0, 0};
#pragma unroll
  for (int t = 0; t < TT; ++t) {
#pragma unroll
    for (int e = 0; e < 4; ++e) cnt[e] += sp[t][e];
  }

  float res[4];
#pragma unroll
  for (int e = 0; e < 4; ++e) {
    const unsigned j = base + (unsigned)e;
    const float w = fminf(fmaxf(w4[e], 0.0f), 8.0f);
    const int c = cnt[e];
    const bool inF = c > 0;
    const bool active = inF | outF;
    // branch index: 0=capture 1=minus 2=search 3=backoff
    // (in_t <= out_t) <=> (8-c <= 8-o) <=> (c >= o)
    const unsigned idx = inF ? (outF ? ((c >= osum) ? 0u : 1u) : 2u) : 3u;
    const unsigned* row = tbl + idx * 40u;

    // p_plus / p_minus exactly as XLA (no FMA contraction)
    const float wn = w * 0.125f;
    const float pp = __fmul_rn(wn, __fsub_rn(2.0f, wn));
    const float pm = __fmul_rn(__fsub_rn(1.0f, wn), __fadd_rn(1.0f, wn));
    const float pA = (idx & 1u) ? pm : pp;   // odd rows use fminus

    // Draw A: fplus/fminus (reuse s-regs across draws to bound VGPR use)
    uintx4 s0 = *reinterpret_cast<const uintx4*>(row);
    uintx4 s1 = *reinterpret_cast<const uintx4*>(row + 4);
    uintx4 s2 = *reinterpret_cast<const uintx4*>(row + 8);
    const unsigned bitsA = tf_sched(s0, s1, s2, j);
    const float u = __uint_as_float((bitsA >> 9) | 0x3f800000u) - 1.0f;
    const bool fab = u < pA;

    // Draw B: gate (ucapture/uminus/usearch/ubackoff)
    s0 = *reinterpret_cast<const uintx4*>(row + 12);
    s1 = *reinterpret_cast<const uintx4*>(row + 16);
    s2 = *reinterpret_cast<const uintx4*>(row + 20);
    const uintx2 tc = *reinterpret_cast<const uintx2*>(row + 36);
    const unsigned bitsB = tf_sched(s0, s1, s2, j);
    const bool gate = (bitsB >> 9) < tc.x;

    // Draw C: umin
    s0 = *reinterpret_cast<const uintx4*>(row + 24);
    s1 = *reinterpret_cast<const uintx4*>(row + 28);
    s2 = *reinterpret_cast<const uintx4*>(row + 32);
    const unsigned bitsC = tf_sched(s0, s1, s2, j);
    const bool um = (bitsC >> 9) < TH_MIN;

    const bool doit = active & gate & (fab | um);
    res[e] = doit ? __fadd_rn(w, __uint_as_float(tc.y)) : w;
  }

  floatx4 r;
  r.x = res[0]; r.y = res[1]; r.z = res[2]; r.w = res[3];
  __builtin_nontemporal_store(r, reinterpret_cast<floatx4*>(out + base));
}

extern "C" void kernel_launch(void* const* d_in, const int* in_sizes, int n_in,
                              void* d_out, int out_size, void* d_ws, size_t ws_size,
                              hipStream_t stream) {
  const int*   inS  = (const int*)d_in[0];
  const int*   outS = (const int*)d_in[1];
  const float* W    = (const float*)d_in[2];
  float*       out  = (float*)d_out;

  // Host-side key derivation (pure arithmetic — graph-capture safe).
  // jax.random.key(42) -> (0, 42). Fold-like split (threefry_partitionable):
  // rk[i] = threefry(key, (0, i));  k7{a,b,c} = threefry(rk7, (0, {0,1,2}))
  unsigned kp[20];
  {
    unsigned rk[16];
    for (unsigned i = 0; i < 8; ++i) {
      unsigned o0, o1;
      tf2x32_host(0u, 42u, 0u, i, o0, o1);
      rk[2 * i] = o0; rk[2 * i + 1] = o1;
    }
    for (int i = 0; i < 14; ++i) kp[i] = rk[i];      // rk0..rk6
    for (unsigned i = 0; i < 3; ++i) {
      unsigned o0, o1;
      tf2x32_host(rk[14], rk[15], 0u, i, o0, o1);
      kp[14 + 2 * i] = o0; kp[15 + 2 * i] = o1;
    }
  }

  // Emit the 12-word injection schedule for key (K0,K1):
  // inj0=(K0,K1) inj1=(K1,ks2+1) inj2=(ks2,K0+2) inj3=(K0,K1+3)
  // inj4=(K1,ks2+4) inj5=(ks2,K0+5)
  auto emit = [](unsigned* d, unsigned K0, unsigned K1) {
    const unsigned ks2 = K0 ^ K1 ^ 0x1BD11BDAu;
    d[0] = K0;  d[1] = K1;       d[2]  = K1;  d[3]  = ks2 + 1u;
    d[4] = ks2; d[5] = K0 + 2u;  d[6]  = K0;  d[7]  = K1 + 3u;
    d[8] = K1;  d[9] = ks2 + 4u; d[10] = ks2; d[11] = K0 + 5u;
  };

  // rows: {drawA keys, drawB keys, drawC keys, thB, sgn}
  Tbl tb;
  const unsigned rowspec[4][8] = {
    {0, 1, 4, 5, 12, 13, TH_CAP10,  0x3f800000u},   // capture  +1
    {2, 3, 6, 7, 14, 15, TH_CAP10,  0xbf800000u},   // minus    -1
    {0, 1, 8, 9, 16, 17, TH_SEARCH, 0x3f800000u},   // search   +1
    {2, 3, 10, 11, 18, 19, TH_BACK, 0xbf800000u},   // backoff  -1
  };
  for (int r = 0; r < 4; ++r) {
    unsigned* d = tb.v + r * 40;
    emit(d,      kp[rowspec[r][0]], kp[rowspec[r][1]]);
    emit(d + 12, kp[rowspec[r][2]], kp[rowspec[r][3]]);
    emit(d + 24, kp[rowspec[r][4]], kp[rowspec[r][5]]);
    d[36] = rowspec[r][6];
    d[37] = rowspec[r][7];
    d[38] = 0; d[39] = 0;
  }

  const int threads = MM / 4;
  dim3 block(256), grid(threads / 256);
  ModSTDP_58823872086838_kernel<<<grid, block, 0, stream>>>(inS, outS, W, out, tb);
}